// Round 11
// baseline (173.937 us; speedup 1.0000x reference)
//
#include <hip/hip_runtime.h>

typedef __bf16 bf16;
typedef __bf16 bf16x4 __attribute__((ext_vector_type(4)));
typedef __bf16 bf16x8 __attribute__((ext_vector_type(8)));
typedef short s16x4 __attribute__((ext_vector_type(4)));
typedef float f32x4 __attribute__((ext_vector_type(4)));
typedef unsigned int u32x4 __attribute__((ext_vector_type(4)));

#define NB 2
#define NT 2048
#define NC 1024
#define NH 16
#define ND 64

#if __has_builtin(__builtin_amdgcn_exp2f)
#define EXP2F(x) __builtin_amdgcn_exp2f(x)
#else
#define EXP2F(x) __expf(0.69314718055994531f * (x))
#endif

#if __has_builtin(__builtin_amdgcn_rcpf)
#define RCPF(x) __builtin_amdgcn_rcpf(x)
#else
#define RCPF(x) (1.0f / (x))
#endif

__device__ __forceinline__ void async16(const void* g, void* l) {
  __builtin_amdgcn_global_load_lds(
      (const __attribute__((address_space(1))) void*)g,
      (__attribute__((address_space(3))) void*)l, 16, 0, 0);
}

__device__ __forceinline__ bf16x8 ld8(const bf16* p) {
  return *reinterpret_cast<const bf16x8*>(p);
}
__device__ __forceinline__ bf16x4 ld4(const bf16* p) {
  return *reinterpret_cast<const bf16x4*>(p);
}

// 16x16x16 bf16 MFMA: A-frag layout == 16x16 C-layout, so P^T feeds B directly
__device__ __forceinline__ f32x4 mfma16(bf16x4 a, bf16x4 b, f32x4 c) {
  s16x4 ai = __builtin_bit_cast(s16x4, a);
  s16x4 bi = __builtin_bit_cast(s16x4, b);
#if __has_builtin(__builtin_amdgcn_mfma_f32_16x16x16bf16_1k)
  return __builtin_amdgcn_mfma_f32_16x16x16bf16_1k(ai, bi, c, 0, 0, 0);
#else
  f32x4 d;
  asm("v_mfma_f32_16x16x16_bf16 %0, %1, %2, %3"
      : "=v"(d) : "v"(ai), "v"(bi), "v"(c));
  return d;
#endif
}

// ---------------- prep: x->bf16 cvt + both weight transposes, one launch ----------------
__global__ __launch_bounds__(256) void prep(
    const float* __restrict__ x, bf16* __restrict__ xb,
    const float* __restrict__ Wa, bf16* __restrict__ Da,
    const float* __restrict__ Wp, bf16* __restrict__ Dp) {
  int bx = blockIdx.x;
  if (bx < 2048) {
    int i = (bx * 256 + threadIdx.x) * 8;
    const float4* s = (const float4*)(x + i);
    float4 a = s[0], b = s[1];
    bf16x8 o;
    o[0] = (bf16)a.x; o[1] = (bf16)a.y; o[2] = (bf16)a.z; o[3] = (bf16)a.w;
    o[4] = (bf16)b.x; o[5] = (bf16)b.y; o[6] = (bf16)b.z; o[7] = (bf16)b.w;
    *(bf16x8*)(xb + i) = o;
    return;
  }
  __shared__ float tile[32][33];
  int idx = bx - 2048;
  const float* src;
  bf16* dst;
  int Cc, cb, rb;
  if (idx < 96 * 32) { src = Wa; dst = Da; Cc = 3072; cb = idx % 96; rb = idx / 96; }
  else { idx -= 96 * 32; src = Wp; dst = Dp; Cc = 1024; cb = idx % 32; rb = idx / 32; }
  int tx = threadIdx.x & 31, ty = threadIdx.x >> 5;
  int r0 = rb * 32, c0 = cb * 32;
#pragma unroll
  for (int i = 0; i < 4; ++i)
    tile[ty + i * 8][tx] = src[(size_t)(r0 + ty + i * 8) * Cc + c0 + tx];
  __syncthreads();
#pragma unroll
  for (int i = 0; i < 4; ++i)
    dst[(size_t)(c0 + ty + i * 8) * 1024 + r0 + tx] = (bf16)tile[tx][ty + i * 8];
}

// ---------------- QKV GEMM: [4096,1024] x [3072,1024]^T (r10, unchanged) ----------------
__global__ __launch_bounds__(256, 3) void gemm_qkv(
    const bf16* __restrict__ A,    // [4096][1024]
    const bf16* __restrict__ Bt,   // [3072][1024]  (W_attn^T)
    const float* __restrict__ bias,// [3072]
    bf16* __restrict__ Qo, bf16* __restrict__ Ko, bf16* __restrict__ Vto) {
  const int K = 1024;
  __shared__ bf16 As[128 * 32];
  __shared__ bf16 Bs[128 * 32];
  const int tid = threadIdx.x;
  const int lane = tid & 63, wv = tid >> 6;
  const int quad = lane >> 4, ln = lane & 15;
  const int m0 = blockIdx.x * 128, n0 = blockIdx.y * 128;
  const int wr = (wv >> 1) * 64, wc = (wv & 1) * 64;
  const int rA = tid >> 2, cA = (tid & 3) * 8;
  f32x4 acc[4][4] = {};

  for (int kt = 0; kt < K / 32; ++kt) {
    const int k0 = kt * 32;
#pragma unroll
    for (int inst = 0; inst < 2; ++inst) {
      async16(A + (size_t)(m0 + inst * 64 + rA) * K + k0 + cA,
              &As[inst * 2048 + wv * 512]);
      async16(Bt + (size_t)(n0 + inst * 64 + rA) * K + k0 + cA,
              &Bs[inst * 2048 + wv * 512]);
    }
    __syncthreads();
    bf16x8 aF[4], bF[4];
#pragma unroll
    for (int i = 0; i < 4; ++i) {
      aF[i] = ld8(&As[(wr + i * 16 + ln) * 32 + quad * 8]);
      bF[i] = ld8(&Bs[(wc + i * 16 + ln) * 32 + quad * 8]);
    }
#pragma unroll
    for (int rb = 0; rb < 4; ++rb)
#pragma unroll
      for (int cb = 0; cb < 4; ++cb)
        acc[rb][cb] = __builtin_amdgcn_mfma_f32_16x16x32_bf16(
            aF[rb], bF[cb], acc[rb][cb], 0, 0, 0);
    __syncthreads();
  }
#pragma unroll
  for (int rb = 0; rb < 4; ++rb) {
#pragma unroll
    for (int cb = 0; cb < 4; ++cb) {
      int gn = n0 + wc + cb * 16 + ln;
      int part = gn >> 10, c = gn & 1023;
      int h = c >> 6, dd = c & 63;
      float bs = bias[gn];
      int gm0 = m0 + wr + rb * 16 + quad * 4;  // 4 consecutive rows
      int b = gm0 >> 11, t0 = gm0 & 2047;
      if (part == 2) {
        bf16x4 vv;
#pragma unroll
        for (int r = 0; r < 4; ++r) vv[r] = (bf16)(acc[rb][cb][r] + bs);
        *(bf16x4*)(Vto + ((size_t)(b * NH + h) * ND + dd) * NT + t0) = vv;
      } else {
        bf16* dst = part == 0 ? Qo : Ko;
        float sc = part == 0 ? 0.18033688f : 1.0f;  // 0.125 * log2(e)
#pragma unroll
        for (int r = 0; r < 4; ++r)
          dst[((size_t)(b * NH + h) * NT + t0 + r) * ND + dd] =
              (bf16)((acc[rb][cb][r] + bs) * sc);
      }
    }
  }
}

// ---------------- flash attention: 128-KEY tiles, half the barriers ----------------
// r10 audit: 512 blocks x 32KB LDS = only 2 barrier-groups/CU; ~45% of cycles
// issue nothing (barrier joins + DMA drains, 34/CU-pipeline). This round keeps
// the r9 wave geometry (8 waves x 16 q-rows, 512 blocks, 2 blocks/CU) but
// stages K[128key][64d] + Vt[64d][128key] per tile (2 bufs x 32KB = 64KB):
// SAME staged bytes, HALF the barrier events, 2x compute per DMA drain.
// Bonus: every wave needs every tile (ktiles = qt+1 uniform; mask only at
// kt == qt) — the per-wave bound and its imbalance disappear.
__global__ __launch_bounds__(512, 4) void flash_attn_kernel(
    const bf16* __restrict__ Qg, const bf16* __restrict__ Kg,
    const bf16* __restrict__ Vtg, bf16* __restrict__ Yg) {
  __shared__ __align__(16) char smem[2][32768];  // [buf][K 16KB | Vt 16KB]
  const int tid = threadIdx.x;
  const int lane = tid & 63, wv = tid >> 6;  // wv in 0..7
  const int quad = lane >> 4, ln = lane & 15;
  const int bid = blockIdx.x;
  const int qt = bid >> 5;  // all 512 blocks co-resident; order irrelevant
  const int bh = bid & 31;
  const int bb = bh >> 4, hh = bh & 15;
  const int q0w = qt * 128 + wv * 16;  // this wave's 16 query rows
  const bf16* Qp = Qg + ((size_t)bh * NT + q0w) * ND;
  const bf16* Kbase = Kg + (size_t)bh * NT * ND;
  const bf16* Vtbase = Vtg + (size_t)bh * ND * NT;

  const int sub8 = lane >> 3, sch8 = lane & 7;     // K: 8x16B chunks per 128B row
  const int sub16 = lane >> 4, sch16 = lane & 15;  // V: 16x16B chunks per 256B row
  const int swz = ln & 7;

  // Q fragments (B-operand of S^T): lane = query, d contiguous
  bf16x8 qf[2];
#pragma unroll
  for (int ks = 0; ks < 2; ++ks)
    qf[ks] = ld8(Qp + (size_t)ln * ND + ks * 32 + quad * 8);

  f32x4 oacc[4] = {};  // O^T: [db]; lane=q, quad*4+r = d within db*16
  float li = 0.f;      // per-quad partial row sum; reduced after the loop

  const int ktiles = qt + 1;  // 128-key tiles; uniform across waves

#define STAGE(KT, P)                                                           \
  {                                                                            \
    const int k0s = (KT) * 128;                                                \
    char* Kl = smem[P];                                                        \
    char* Vl = smem[P] + 16384;                                                \
    _Pragma("unroll") for (int i = 0; i < 2; ++i) {                            \
      int r0 = wv * 16 + i * 8;                                                \
      int row = r0 + sub8;                                                     \
      int gch = sch8 ^ (row & 7);                                              \
      async16(Kbase + (size_t)(k0s + row) * ND + gch * 8, Kl + r0 * 128);      \
    }                                                                          \
    _Pragma("unroll") for (int i = 0; i < 2; ++i) {                            \
      int r0 = wv * 8 + i * 4;                                                 \
      int row = r0 + sub16;                                                    \
      int gch = sch16 ^ (row & 15);                                            \
      async16(Vtbase + (size_t)row * NT + k0s + gch * 8, Vl + r0 * 256);       \
    }                                                                          \
  }

  STAGE(0, 0);
  for (int kt = 0; kt < ktiles; ++kt) {
    const int p = kt & 1;
    __syncthreads();  // drains DMA for tile kt
    if (kt + 1 < ktiles) STAGE(kt + 1, p ^ 1);
    const char* Kl = smem[p];
    const char* Vl = smem[p] + 16384;
    const int k0 = kt * 128;
    // S^T = K·Q^T over 128 keys
    f32x4 sacc[8] = {};  // [cb]; lane=q, quad*4+r = key within cb*16
#pragma unroll
    for (int ks = 0; ks < 2; ++ks) {
      bf16x8 kfr[8];
#pragma unroll
      for (int cb = 0; cb < 8; ++cb)
        kfr[cb] = *(const bf16x8*)(Kl + (cb * 16 + ln) * 128 +
                                   (((ks * 4 + quad) ^ swz) * 16));
#pragma unroll
      for (int cb = 0; cb < 8; ++cb)
        sacc[cb] = __builtin_amdgcn_mfma_f32_16x16x32_bf16(
            kfr[cb], qf[ks], sacc[cb], 0, 0, 0);
    }
    if (kt == qt) {  // causal mask: only the diagonal 128-key tile
      int qr = q0w + ln;
#pragma unroll
      for (int cb = 0; cb < 8; ++cb)
#pragma unroll
        for (int r = 0; r < 4; ++r) {
          int kc = k0 + cb * 16 + quad * 4 + r;
          if (kc > qr) sacc[cb][r] = -1e30f;
        }
    }
    // no-max softmax: P = exp2(S) directly (scale folded into Q)
    bf16x4 pf[8];
    float rs = 0.f;
#pragma unroll
    for (int cb = 0; cb < 8; ++cb) {
      bf16x4 pv;
#pragma unroll
      for (int r = 0; r < 4; ++r) {
        float pexp = EXP2F(sacc[cb][r]);
        rs += pexp;
        pv[r] = (bf16)pexp;
      }
      pf[cb] = pv;
    }
    li += rs;
    // O^T += V^T·P^T
#pragma unroll
    for (int cb = 0; cb < 8; ++cb) {
      bf16x4 vfr[4];
#pragma unroll
      for (int db = 0; db < 4; ++db)
        vfr[db] = *(const bf16x4*)(Vl + (db * 16 + ln) * 256 +
                                   (((cb * 2 + (quad >> 1)) ^ ln) * 16) +
                                   (quad & 1) * 8);
#pragma unroll
      for (int db = 0; db < 4; ++db)
        oacc[db] = mfma16(vfr[db], pf[cb], oacc[db]);
    }
  }
#undef STAGE

  // complete the row sum across quads
  li += __shfl_xor(li, 16);
  li += __shfl_xor(li, 32);

  float inv = RCPF(li);
  int row = q0w + ln;
#pragma unroll
  for (int db = 0; db < 4; ++db) {
    bf16x4 ov;
#pragma unroll
    for (int r = 0; r < 4; ++r) ov[r] = (bf16)(oacc[db][r] * inv);
    *(bf16x4*)(Yg + ((size_t)(bb * NT + row)) * NC + hh * 64 + db * 16 +
               quad * 4) = ov;
  }
}

// ---------------- proj GEMM: 128x64 tiles -> 512 blocks = 2/CU (r10, unchanged) ----------------
__global__ __launch_bounds__(256, 2) void gemm_proj(
    const bf16* __restrict__ A,    // [4096][1024]  (y)
    const bf16* __restrict__ Bt,   // [1024][1024]  (W_proj^T)
    const float* __restrict__ bias,// [1024]
    float* __restrict__ out) {     // [4096][1024]
  const int K = 1024;
  __shared__ bf16 As[128 * 32];
  __shared__ bf16 Bs[64 * 32];
  const int tid = threadIdx.x;
  const int lane = tid & 63, wv = tid >> 6;
  const int quad = lane >> 4, ln = lane & 15;
  const int m0 = blockIdx.x * 128, n0 = blockIdx.y * 64;
  const int wr = wv * 32;
  const int rA = tid >> 2, cA = (tid & 3) * 8;
  f32x4 acc[2][4] = {};

  for (int kt = 0; kt < K / 32; ++kt) {
    const int k0 = kt * 32;
#pragma unroll
    for (int inst = 0; inst < 2; ++inst)
      async16(A + (size_t)(m0 + inst * 64 + rA) * K + k0 + cA,
              &As[inst * 2048 + wv * 512]);
    async16(Bt + (size_t)(n0 + rA) * K + k0 + cA, &Bs[wv * 512]);
    __syncthreads();
    bf16x8 aF[2], bF[4];
#pragma unroll
    for (int i = 0; i < 2; ++i)
      aF[i] = ld8(&As[(wr + i * 16 + ln) * 32 + quad * 8]);
#pragma unroll
    for (int i = 0; i < 4; ++i)
      bF[i] = ld8(&Bs[(i * 16 + ln) * 32 + quad * 8]);
#pragma unroll
    for (int rb = 0; rb < 2; ++rb)
#pragma unroll
      for (int cb = 0; cb < 4; ++cb)
        acc[rb][cb] = __builtin_amdgcn_mfma_f32_16x16x32_bf16(
            aF[rb], bF[cb], acc[rb][cb], 0, 0, 0);
    __syncthreads();
  }
#pragma unroll
  for (int rb = 0; rb < 2; ++rb) {
#pragma unroll
    for (int cb = 0; cb < 4; ++cb) {
      int gn = n0 + cb * 16 + ln;
      float bs = bias[gn];
#pragma unroll
      for (int r = 0; r < 4; ++r) {
        int gm = m0 + wr + rb * 16 + quad * 4 + r;
        out[(size_t)gm * 1024 + gn] = acc[rb][cb][r] + bs;
      }
    }
  }
}

extern "C" void kernel_launch(void* const* d_in, const int* in_sizes, int n_in,
                              void* d_out, int out_size, void* d_ws, size_t ws_size,
                              hipStream_t stream) {
  const float* x      = (const float*)d_in[0];
  const float* W_attn = (const float*)d_in[1];
  const float* b_attn = (const float*)d_in[2];
  const float* W_proj = (const float*)d_in[3];
  const float* b_proj = (const float*)d_in[4];
  float* out = (float*)d_out;

  bf16* ws  = (bf16*)d_ws;
  bf16* xb  = ws;                          // 4096*1024; becomes Y after gemm_qkv
  bf16* Wab = xb + (size_t)4096 * 1024;    // 3072*1024
  bf16* Wpb = Wab + (size_t)3072 * 1024;   // 1024*1024
  bf16* Qb  = Wpb + (size_t)1024 * 1024;   // 32*2048*64
  bf16* Kb  = Qb + (size_t)32 * 2048 * 64;
  bf16* Vtb = Kb + (size_t)32 * 2048 * 64; // [B,H,D,T] written by gemm_qkv
  bf16* Yb  = xb;                          // alias: xb dead after gemm_qkv

  prep<<<2048 + 96 * 32 + 32 * 32, 256, 0, stream>>>(x, xb, W_attn, Wab,
                                                     W_proj, Wpb);
  gemm_qkv<<<dim3(32, 24), 256, 0, stream>>>(xb, Wab, b_attn, Qb, Kb, Vtb);
  flash_attn_kernel<<<512, 512, 0, stream>>>(Qb, Kb, Vtb, Yb);
  gemm_proj<<<dim3(32, 16), 256, 0, stream>>>(Yb, Wpb, b_proj, out);
}